// Round 1
// baseline (211.010 us; speedup 1.0000x reference)
//
#include <hip/hip_runtime.h>
#include <math.h>

// ---------------------------------------------------------------------------
// PreLossSampler: reg_valid, NMS over gt boxes (rotated BEV IoU), IoU3D
// pred-vs-masked-gt with per-row max/argmax.
// N = 1024 fixed.
// Workspace layout (d_ws):
//   [0,      4096)   int   order[1024]      (argsort(-labels), stable)
//   [4096,  36864)   float sbox[1024*8]     (gt boxes gathered in sorted order)
//   [36864, 40960)   int   sampled[1024]    (NMS keep mask, original index space)
//   [40960, 172032)  u64   sup[1024*16]     (suppression bitmask, sorted space)
// Output (float32 x 4096): [reg_valid | labels | max_overlaps | gt_assignment]
// ---------------------------------------------------------------------------

#define NB 1024

__device__ __forceinline__ bool pt_in_box(float px, float py,
        float bx, float by, float bdx, float bdy, float cs, float sn) {
    // reference: rotate delta by -r; cos(-r)=cs, sin(-r)=-sn
    float dx = px - bx, dy = py - by;
    float lx = dx * cs + dy * sn;
    float ly = dy * cs - dx * sn;
    return (fabsf(lx) <= bdx * 0.5f + 1e-5f) && (fabsf(ly) <= bdy * 0.5f + 1e-5f);
}

// Rotated-rectangle intersection area, replicating the reference's candidate
// construction order (a-corners, b-corners, 16 edge-pair intersections),
// stable ascending sort by atan2 about the valid-point centroid, shoelace.
__device__ float rect_inter_area(
        float ax, float ay, float adx, float ady, float ar,
        float bx, float by, float bdx, float bdy, float br) {
    // Circumscribed-circle reject. If circles (inflated by the 1e-5
    // containment epsilon, margin 1e-3) are disjoint, the reference finds
    // k=0 valid candidates -> area 0. Exactly value-preserving.
    float dcx = ax - bx, dcy = ay - by;
    float ra = 0.5f * sqrtf(adx * adx + ady * ady);
    float rb = 0.5f * sqrtf(bdx * bdx + bdy * bdy);
    float lim = ra + rb + 1e-3f;
    if (dcx * dcx + dcy * dcy > lim * lim) return 0.0f;

    float csa = cosf(ar), sna = sinf(ar);
    float csb = cosf(br), snb = sinf(br);
    float cax[4], cay[4], cbx[4], cby[4];
    const float SX[4] = {0.5f, 0.5f, -0.5f, -0.5f};
    const float SY[4] = {0.5f, -0.5f, -0.5f, 0.5f};
#pragma unroll
    for (int i = 0; i < 4; ++i) {
        float lx = SX[i] * adx, ly = SY[i] * ady;
        cax[i] = lx * csa - ly * sna + ax;
        cay[i] = lx * sna + ly * csa + ay;
        float mx = SX[i] * bdx, my = SY[i] * bdy;
        cbx[i] = mx * csb - my * snb + bx;
        cby[i] = mx * snb + my * csb + by;
    }

    // Candidate points, compacted but in the reference's index order
    // (0..3 a-corners, 4..7 b-corners, 8..23 intersections i*4+j) so the
    // stable angle-sort tie-break matches jnp.argsort(stable).
    float qx[24], qy[24];
    int m = 0;
#pragma unroll
    for (int i = 0; i < 4; ++i)
        if (pt_in_box(cax[i], cay[i], bx, by, bdx, bdy, csb, snb)) {
            qx[m] = cax[i]; qy[m] = cay[i]; ++m;
        }
#pragma unroll
    for (int i = 0; i < 4; ++i)
        if (pt_in_box(cbx[i], cby[i], ax, ay, adx, ady, csa, sna)) {
            qx[m] = cbx[i]; qy[m] = cby[i]; ++m;
        }
#pragma unroll
    for (int i = 0; i < 4; ++i) {
        float a0x = cax[i], a0y = cay[i];
        float d1x = cax[(i + 1) & 3] - a0x, d1y = cay[(i + 1) & 3] - a0y;
#pragma unroll
        for (int j = 0; j < 4; ++j) {
            float b0x = cbx[j], b0y = cby[j];
            float d2x = cbx[(j + 1) & 3] - b0x, d2y = cby[(j + 1) & 3] - b0y;
            float r0x = b0x - a0x, r0y = b0y - a0y;
            float den = d1x * d2y - d1y * d2x;
            bool nz = fabsf(den) > 1e-8f;
            float sden = nz ? den : 1.0f;
            float t = (r0x * d2y - r0y * d2x) / sden;
            float u = (r0x * d1y - r0y * d1x) / sden;
            if (nz && t >= 0.0f && t <= 1.0f && u >= 0.0f && u <= 1.0f) {
                qx[m] = a0x + t * d1x;
                qy[m] = a0y + t * d1y;
                ++m;
            }
        }
    }
    if (m < 3) return 0.0f;

    float sx = 0.0f, sy = 0.0f;
    for (int i = 0; i < m; ++i) { sx += qx[i]; sy += qy[i]; }
    float ctrx = sx / (float)m, ctry = sy / (float)m;
    float va[24];
    for (int i = 0; i < m; ++i) {
        float cx = qx[i] - ctrx, cy = qy[i] - ctry;
        qx[i] = cx; qy[i] = cy;
        va[i] = atan2f(cy, cx);
    }
    // stable insertion sort, ascending angle
    for (int i = 1; i < m; ++i) {
        float kx = qx[i], ky = qy[i], ka = va[i];
        int j = i - 1;
        while (j >= 0 && va[j] > ka) {
            qx[j + 1] = qx[j]; qy[j + 1] = qy[j]; va[j + 1] = va[j];
            --j;
        }
        qx[j + 1] = kx; qy[j + 1] = ky; va[j + 1] = ka;
    }
    float s = 0.0f;
    for (int i = 0; i < m; ++i) {
        int n2 = (i + 1 < m) ? i + 1 : 0;
        s += qx[i] * qy[n2] - qy[i] * qx[n2];
    }
    return 0.5f * fabsf(s);
}

// ---------------------------------------------------------------------------
// Kernel A: reg_valid + label copy + bitonic argsort(-labels) + gather boxes.
// ---------------------------------------------------------------------------
__global__ __launch_bounds__(1024) void prep_kernel(
        const float* __restrict__ labels, const float* __restrict__ cls,
        const float* __restrict__ gt, float* __restrict__ out,
        int* __restrict__ order, float* __restrict__ sbox) {
    int tid = threadIdx.x;
    float lab = labels[tid];
    float sig = 1.0f / (1.0f + expf(-cls[tid]));
    out[tid] = (sig > 0.55f && lab > 0.55f) ? 1.0f : 0.0f;
    out[NB + tid] = lab;

    __shared__ float key[NB];
    __shared__ int   idx[NB];
    key[tid] = lab;
    idx[tid] = tid;
    __syncthreads();
    // sort: descending key, ascending idx on ties (== stable argsort(-key))
    for (int k = 2; k <= NB; k <<= 1) {
        for (int j = k >> 1; j > 0; j >>= 1) {
            int p = tid ^ j;
            if (p > tid) {
                float k1 = key[tid], k2 = key[p];
                int   i1 = idx[tid], i2 = idx[p];
                // lessPT: element at p should precede element at tid
                bool lessPT = (k2 > k1) || (k2 == k1 && i2 < i1);
                bool asc = (tid & k) == 0;
                bool doswap = asc ? lessPT : !lessPT;
                if (doswap) {
                    key[tid] = k2; key[p] = k1;
                    idx[tid] = i2; idx[p] = i1;
                }
            }
            __syncthreads();
        }
    }
    int o = idx[tid];
    order[tid] = o;
#pragma unroll
    for (int c = 0; c < 7; ++c) sbox[tid * 8 + c] = gt[o * 8 + c];
    sbox[tid * 8 + 7] = 0.0f;
}

// ---------------------------------------------------------------------------
// Kernel B: suppression bitmask in sorted space.
// grid (4, 1024), block 256. wave w of block bx owns word bx*4+w of row i.
// ---------------------------------------------------------------------------
__global__ __launch_bounds__(256) void sup_kernel(
        const float* __restrict__ sbox, unsigned long long* __restrict__ sup) {
    int i = blockIdx.y;
    int j = blockIdx.x * 256 + threadIdx.x;
    int word = j >> 6;
    int lane = threadIdx.x & 63;
    // wave-uniform skip: whole word has j <= i
    int wmaxj = (word << 6) + 63;
    if (wmaxj <= i) {
        if (lane == 0) sup[i * 16 + word] = 0ULL;
        return;
    }
    bool pred = false;
    if (j > i) {
        const float* A = &sbox[i * 8];
        const float* B = &sbox[j * 8];
        float inter = rect_inter_area(A[0], A[1], A[3], A[4], A[6],
                                      B[0], B[1], B[3], B[4], B[6]);
        float sa = A[3] * A[4];
        float sb = B[3] * B[4];
        float iou = inter / fmaxf(sa + sb - inter, 1e-8f);
        pred = iou > 0.1f;
    }
    unsigned long long m = __ballot(pred);
    if (lane == 0) sup[i * 16 + word] = m;
}

// ---------------------------------------------------------------------------
// Kernel C: sequential greedy NMS on the bitmask; scatter keep to original
// index space. One block of 1024 threads; wave 0 runs the sequential part
// with the 1024-bit keep mask held in lanes 0..15 (u64 each). Suppression
// matrix staged through LDS in 4 phases of 256 rows (32 KB).
// ---------------------------------------------------------------------------
__global__ __launch_bounds__(1024) void nms_seq_kernel(
        const unsigned long long* __restrict__ sup,
        const int* __restrict__ order, int* __restrict__ sampled) {
    __shared__ unsigned long long sup_s[256 * 16];
    __shared__ unsigned long long keep_s[16];
    int tid = threadIdx.x;
    unsigned long long kw = ~0ULL;  // lanes 0..15: keep words

    for (int phase = 0; phase < 4; ++phase) {
        for (int t = tid; t < 256 * 16; t += 1024)
            sup_s[t] = sup[phase * (256 * 16) + t];
        __syncthreads();
        if (tid < 64) {
            for (int w = phase * 4; w < phase * 4 + 4; ++w) {
                int b = -1;
                while (true) {
                    unsigned long long cur = __shfl(kw, w, 64);
                    unsigned long long mask =
                        (b < 0) ? ~0ULL
                                : ((b >= 63) ? 0ULL : (~0ULL << (b + 1)));
                    unsigned long long rem = cur & mask;
                    if (!rem) break;
                    b = __ffsll((unsigned long long)rem) - 1;
                    int ii = (w * 64 + b) - phase * 256;  // row within phase
                    if (tid < 16) kw &= ~sup_s[ii * 16 + tid];
                }
            }
        }
        __syncthreads();
    }
    if (tid < 16) keep_s[tid] = kw;
    __syncthreads();
    int bit = (int)((keep_s[tid >> 6] >> (tid & 63)) & 1ULL);
    sampled[order[tid]] = bit;
}

// ---------------------------------------------------------------------------
// Kernel D: iou3d row i (pred box i vs all masked gt), block-wide
// (max, first-index) reduction, thresholding, outputs 2 & 3.
// ---------------------------------------------------------------------------
__global__ __launch_bounds__(1024) void iou3d_kernel(
        const float* __restrict__ pred, const float* __restrict__ gt,
        const int* __restrict__ sampled, float* __restrict__ out) {
    int i = blockIdx.x;
    int j = threadIdx.x;
    float Ax = pred[i * 7 + 0], Ay = pred[i * 7 + 1], Az = pred[i * 7 + 2];
    float Adx = pred[i * 7 + 3], Ady = pred[i * 7 + 4], Adz = pred[i * 7 + 5];
    float Ar = pred[i * 7 + 6];

    float msk = sampled[j] ? 1.0f : 0.0f;
    float Bx = gt[j * 8 + 0] * msk, By = gt[j * 8 + 1] * msk;
    float Bz = gt[j * 8 + 2] * msk;
    float Bdx = gt[j * 8 + 3] * msk, Bdy = gt[j * 8 + 4] * msk;
    float Bdz = gt[j * 8 + 5] * msk;
    float Br = gt[j * 8 + 6] * msk;

    float inter = rect_inter_area(Ax, Ay, Adx, Ady, Ar, Bx, By, Bdx, Bdy, Br);
    float amax = Az + Adz * 0.5f, amin = Az - Adz * 0.5f;
    float bmax = Bz + Bdz * 0.5f, bmin = Bz - Bdz * 0.5f;
    float oh = fmaxf(fminf(amax, bmax) - fmaxf(amin, bmin), 0.0f);
    float inter3d = inter * oh;
    float va = Adx * Ady * Adz, vb = Bdx * Bdy * Bdz;
    float iou = inter3d / fmaxf(va + vb - inter3d, 1e-8f);

    // (max value, first index) reduction — matches jnp.argmax tie-break
    float bv = iou;
    int bi = j;
#pragma unroll
    for (int off = 32; off > 0; off >>= 1) {
        float ov = __shfl_down(bv, off, 64);
        int oi = __shfl_down(bi, off, 64);
        if (ov > bv || (ov == bv && oi < bi)) { bv = ov; bi = oi; }
    }
    __shared__ float wv[16];
    __shared__ int wi[16];
    int lane = threadIdx.x & 63, wid = threadIdx.x >> 6;
    if (lane == 0) { wv[wid] = bv; wi[wid] = bi; }
    __syncthreads();
    if (threadIdx.x == 0) {
        float fv = wv[0];
        int fi = wi[0];
#pragma unroll
        for (int t = 1; t < 16; ++t) {
            if (wv[t] > fv || (wv[t] == fv && wi[t] < fi)) { fv = wv[t]; fi = wi[t]; }
        }
        float mo = (fv > 0.75f) ? 1.0f : ((fv < 0.25f) ? 0.0f : fv);
        out[2 * NB + i] = mo;
        out[3 * NB + i] = (float)fi;
    }
}

extern "C" void kernel_launch(void* const* d_in, const int* in_sizes, int n_in,
                              void* d_out, int out_size, void* d_ws, size_t ws_size,
                              hipStream_t stream) {
    const float* labels = (const float*)d_in[0];  // rcnn_cls_labels (1024)
    const float* pred   = (const float*)d_in[1];  // pred_boxes (1024*7)
    const float* gt     = (const float*)d_in[2];  // gt_boxes   (1024*8)
    const float* cls    = (const float*)d_in[3];  // rcnn_cls   (1024)
    float* out = (float*)d_out;

    char* ws = (char*)d_ws;
    int* order = (int*)ws;                                   // 4 KB
    float* sbox = (float*)(ws + 4096);                       // 32 KB
    int* sampled = (int*)(ws + 4096 + 32768);                // 4 KB
    unsigned long long* sup =
        (unsigned long long*)(ws + 4096 + 32768 + 4096);     // 128 KB

    prep_kernel<<<1, 1024, 0, stream>>>(labels, cls, gt, out, order, sbox);
    sup_kernel<<<dim3(4, 1024), 256, 0, stream>>>(sbox, sup);
    nms_seq_kernel<<<1, 1024, 0, stream>>>(sup, order, sampled);
    iou3d_kernel<<<1024, 1024, 0, stream>>>(pred, gt, sampled, out);
}